// Round 4
// baseline (1077.056 us; speedup 1.0000x reference)
//
#include <hip/hip_runtime.h>
#include <math.h>

#define B_   4
#define T_   20000
#define SUB  20
#define ENO  2000
#define INO  500
#define HID  10
#define NCOS 24
#define TNO  200

// ---------------- prep 1: softmax over subunit axis; CwP = padded slice-major C*exp(scale); e2 = exp(W2)
// CwPE layout: [(z*SUB + s)*512 + e'] for e' in [0,500), z = e/500. Pads [500,512) zeroed here too.
__global__ __launch_bounds__(256) void prep1_kernel(
    const float* __restrict__ Ce_raw, const float* __restrict__ Ci_raw,
    const float* __restrict__ ge, const float* __restrict__ gi,
    const float* __restrict__ Es, const float* __restrict__ Is,
    const float* __restrict__ W2, const int* __restrict__ testp,
    float* __restrict__ outCe, float* __restrict__ outCi,
    float* __restrict__ CwPE, float* __restrict__ CwPI, float* __restrict__ e2)
{
  int idx = blockIdx.x * 256 + threadIdx.x;
  int test = *testp;
  float scale = test ? 10000.f : 1000.f;
  if (idx < ENO + INO) {
    const float* raw; const float* g; float* outC; int n, col; float sc;
    if (idx < ENO) { raw = Ce_raw; g = ge; outC = outCe; n = ENO; col = idx;       sc = expf(Es[col]); }
    else           { raw = Ci_raw; g = gi; outC = outCi; n = INO; col = idx - ENO; sc = expf(Is[col]); }
    float v[SUB]; float m = -1e30f;
    #pragma unroll
    for (int s = 0; s < SUB; s++) {
      float x = raw[s * n + col];
      if (!test) x += g[s * n + col];
      x *= scale;
      v[s] = x; m = fmaxf(m, x);
    }
    float sum = 0.f;
    #pragma unroll
    for (int s = 0; s < SUB; s++) { v[s] = expf(v[s] - m); sum += v[s]; }
    float inv = 1.f / sum;
    if (idx < ENO) {
      int z = col / 500, e2c = col - z * 500;
      #pragma unroll
      for (int s = 0; s < SUB; s++) {
        float c = v[s] * inv; outC[s * n + col] = c;
        CwPE[((long)(z * SUB + s)) * 512 + e2c] = c * sc;
      }
    } else {
      #pragma unroll
      for (int s = 0; s < SUB; s++) {
        float c = v[s] * inv; outC[s * n + col] = c;
        CwPI[(long)s * 512 + col] = c * sc;
      }
    }
  } else if (idx < ENO + INO + SUB * HID) {
    int j = idx - (ENO + INO);
    e2[j] = expf(W2[j]);
  } else if (idx < ENO + INO + SUB * HID + 960 + 240) {
    int j = idx - (ENO + INO + SUB * HID);
    if (j < 960) { int z = j / 240, s = (j / 12) % SUB, c = j % 12; CwPE[((long)(z * SUB + s)) * 512 + 500 + c] = 0.f; }
    else         { int j2 = j - 960; int s = j2 / 12, c = j2 % 12;  CwPI[(long)s * 512 + 500 + c] = 0.f; }
  }
}

// ---------------- prep 2: effective kernels Keff[src][s][h][d] = sum_k W[s*HID+h,k] * basis(k,d)
__global__ __launch_bounds__(256) void prep2_kernel(
    const float* __restrict__ We, const float* __restrict__ Wi, float* __restrict__ Keff)
{
  int idx = blockIdx.x * 256 + threadIdx.x;
  if (idx >= 2 * SUB * HID * TNO) return;
  int d   = idx % TNO;
  int sh  = (idx / TNO) % (SUB * HID);
  int src = idx / (TNO * SUB * HID);
  const float* W = src ? Wi : We;           // [SUB*HID][NCOS]
  const float PIF = 3.14159265358979323846f;
  float raw = 6.0f * logf((float)d + 1.0f + 1e-7f);
  float acc = 0.f;
  #pragma unroll
  for (int k = 0; k < NCOS; k++) {
    float ph = 1.57079632679489662f * (float)k;
    if (raw >= ph - PIF && raw <= ph + PIF) {
      acc += W[sh * NCOS + k] * (0.5f * cosf(raw - ph) + 0.5f);
    }
  }
  Keff[idx] = acc;
}

// ---------------- GEMM: syn[b][s][t] = sum_e S[b,t,e] * Cw[s,e]
// Block = 16 t-rows x full K (z-loop over five 500-e slices). S staged as contiguous
// 2000B row-runs into 33.8KB LDS (stride 528: minimal bank aliasing). Cw read straight
// from global CwP (L1/L2-resident, 256B coalesced segments per wave) -- no Cw LDS.
// Lane split: rp=l&3 (4-way rows), ep=l>>2 (16-way e). Tail: 4-mask shfl_xor reduce.
// Next-slice S issued to registers before the barrier (latency hides under compute).
__global__ __launch_bounds__(256, 4) void gemm_syn_kernel(
    const float* __restrict__ S_e, const float* __restrict__ S_i,
    const float* __restrict__ CwPE, const float* __restrict__ CwPI,
    float* __restrict__ synE, float* __restrict__ synI)
{
  const int b  = blockIdx.y;
  const int t0 = blockIdx.x * 16;
  __shared__ __align__(16) float sS[16 * 528];

  const int tid = threadIdx.x;
  const int l   = tid & 63;
  const int w   = tid >> 6;
  const int s0  = w * 5;
  const int rp  = l & 3;
  const int ep  = l >> 2;

  // zero e-pad columns [500,512) once (staging never writes them)
  if (tid < 192) { int r = tid / 12, c = tid % 12; sS[r * 528 + 500 + c] = 0.f; }

  float acc[4][5] = {};
  float4 pS[8];

  const long rowE = ((long)b * T_ + t0) * ENO;
  const long rowI = ((long)b * T_ + t0) * INO;

  // prologue: issue slice 0 loads
  #pragma unroll
  for (int p = 0; p < 8; p++) {
    int u = tid + 256 * p;
    if (u < 2000) { int r = u / 125, k = u - r * 125; pS[p] = *(const float4*)&S_e[rowE + (long)r * ENO + 4 * k]; }
  }

  for (int z = 0; z < 5; z++) {
    const bool isE = (z < 4);
    // commit staged regs -> LDS
    #pragma unroll
    for (int p = 0; p < 8; p++) {
      int u = tid + 256 * p;
      if (u < 2000) { int r = u / 125, k = u - r * 125; *(float4*)&sS[r * 528 + 4 * k] = pS[p]; }
    }
    // issue next slice (completes during compute)
    if (z < 4) {
      const bool nE = (z + 1 < 4);
      const float* __restrict__ src = nE ? (S_e + rowE + (z + 1) * 500) : (S_i + rowI);
      const int rs = nE ? ENO : INO;
      #pragma unroll
      for (int p = 0; p < 8; p++) {
        int u = tid + 256 * p;
        if (u < 2000) { int r = u / 125, k = u - r * 125; pS[p] = *(const float4*)&src[(long)r * rs + 4 * k]; }
      }
    }
    __syncthreads();

    const float* __restrict__ cwb = isE ? (CwPE + ((long)z * SUB) * 512) : CwPI;
    #pragma unroll
    for (int step = 0; step < 8; step++) {
      const int e = 4 * ep + 64 * step;
      float4 cw[5];
      #pragma unroll
      for (int j = 0; j < 5; j++) cw[j] = *(const float4*)&cwb[(s0 + j) * 512 + e];
      #pragma unroll
      for (int tt = 0; tt < 4; tt++) {
        float4 sv = *(float4*)&sS[(rp + 4 * tt) * 528 + e];
        #pragma unroll
        for (int j = 0; j < 5; j++) {
          acc[tt][j] += sv.x * cw[j].x;
          acc[tt][j] += sv.y * cw[j].y;
          acc[tt][j] += sv.z * cw[j].z;
          acc[tt][j] += sv.w * cw[j].w;
        }
      }
    }

    if (z >= 3) {
      // reduce over ep (lane bits 2..5)
      #pragma unroll
      for (int mask = 4; mask <= 32; mask <<= 1)
        #pragma unroll
        for (int tt = 0; tt < 4; tt++)
          #pragma unroll
          for (int j = 0; j < 5; j++)
            acc[tt][j] += __shfl_xor(acc[tt][j], mask, 64);
      float* __restrict__ dst = (z == 3) ? synE : synI;
      if (l < 4) {
        #pragma unroll
        for (int j = 0; j < 5; j++)
          #pragma unroll
          for (int tt = 0; tt < 4; tt++)
            dst[((long)b * SUB + s0 + j) * T_ + t0 + rp + 4 * tt] = acc[tt][j];
      }
      #pragma unroll
      for (int tt = 0; tt < 4; tt++)
        #pragma unroll
        for (int j = 0; j < 5; j++) acc[tt][j] = 0.f;
    }
    __syncthreads();
  }
}

// ---------------- conv: pre[h,t] = sum_d Ke[h,d]*syn_e[t-d] + Ki[h,d]*syn_i[t-d]; tanh; combine over h
__global__ __launch_bounds__(256, 2) void conv_kernel(
    const float* __restrict__ synE, const float* __restrict__ synI,
    const float* __restrict__ Keff, const float* __restrict__ e2,
    const float* __restrict__ b1, float* __restrict__ sub_bst)
{
  const int chunk = blockIdx.x;       // 0..19
  const int s = blockIdx.y;
  const int b = blockIdx.z;
  const int cs = chunk * 1000;

  __shared__ __align__(16) float se[1200];
  __shared__ __align__(16) float si[1200];
  __shared__ __align__(16) float te[HID * TNO];
  __shared__ __align__(16) float ti[HID * TNO];
  __shared__ float se2[HID], sb[HID];

  const int tid = threadIdx.x;
  const float* __restrict__ pe = &synE[((long)b * SUB + s) * T_];
  const float* __restrict__ pin = &synI[((long)b * SUB + s) * T_];

  for (int i4 = tid; i4 < 300; i4 += 256) {
    int gt = cs - 200 + i4 * 4;
    float4 ve = make_float4(0.f, 0.f, 0.f, 0.f);
    float4 vi = make_float4(0.f, 0.f, 0.f, 0.f);
    if (gt >= 0) { ve = *(const float4*)&pe[gt]; vi = *(const float4*)&pin[gt]; }
    *(float4*)&se[i4 * 4] = ve;
    *(float4*)&si[i4 * 4] = vi;
  }
  const float* __restrict__ ke = &Keff[(long)s * HID * TNO];
  const float* __restrict__ ki = &Keff[((long)SUB + s) * HID * TNO];
  for (int i4 = tid; i4 < 500; i4 += 256) {
    *(float4*)&te[i4 * 4] = *(const float4*)&ke[i4 * 4];
    *(float4*)&ti[i4 * 4] = *(const float4*)&ki[i4 * 4];
  }
  if (tid < HID) { se2[tid] = e2[s * HID + tid]; sb[tid] = b1[s * HID + tid]; }
  __syncthreads();

  if (tid >= 250) return;
  const int lofs = 200 + 4 * tid;
  float so[4] = {0.f, 0.f, 0.f, 0.f};

  #pragma unroll
  for (int half = 0; half < 2; half++) {
    const int h0 = half * 5;
    float acc[5][4] = {};
    float we[8], wi[8];
    *(float4*)&we[4] = *(float4*)&se[lofs];
    *(float4*)&wi[4] = *(float4*)&si[lofs];
    for (int dstep = 0; dstep < 50; dstep++) {
      const int d0 = dstep * 4;
      *(float4*)&we[0] = *(float4*)&se[lofs - d0 - 4];
      *(float4*)&wi[0] = *(float4*)&si[lofs - d0 - 4];
      float4 tpe[5], tpi[5];
      #pragma unroll
      for (int h = 0; h < 5; h++) {
        tpe[h] = *(float4*)&te[(h0 + h) * TNO + d0];
        tpi[h] = *(float4*)&ti[(h0 + h) * TNO + d0];
      }
      #pragma unroll
      for (int dd = 0; dd < 4; dd++) {
        #pragma unroll
        for (int h = 0; h < 5; h++) {
          float tapeh = ((float*)&tpe[h])[dd];
          float tapih = ((float*)&tpi[h])[dd];
          #pragma unroll
          for (int j = 0; j < 4; j++) {
            acc[h][j] += tapeh * we[4 + j - dd];
            acc[h][j] += tapih * wi[4 + j - dd];
          }
        }
      }
      #pragma unroll
      for (int m = 0; m < 4; m++) { we[4 + m] = we[m]; wi[4 + m] = wi[m]; }
    }
    #pragma unroll
    for (int h = 0; h < 5; h++) {
      float eh = se2[h0 + h], bh = sb[h0 + h];
      #pragma unroll
      for (int j = 0; j < 4; j++) so[j] += eh * tanhf(acc[h][j] + bh);
    }
  }
  int t0 = cs + 4 * tid;
  *(float4*)&sub_bst[((long)b * SUB + s) * T_ + t0] = *(float4*)&so[0];
}

// ---------------- final: transpose sub_bst[b][s][t] -> sub_out[b][t][s], final[b][t] = sum_s + V_o
__global__ __launch_bounds__(256) void final_kernel(
    const float* __restrict__ sub_bst, const float* __restrict__ Vo,
    float* __restrict__ out_final, float* __restrict__ out_sub)
{
  int t = blockIdx.x * 256 + threadIdx.x;
  int b = blockIdx.y;
  if (t >= T_) return;
  float vo = Vo[0];
  float sum = 0.f;
  #pragma unroll
  for (int s = 0; s < SUB; s++) {
    float v = sub_bst[((long)b * SUB + s) * T_ + t];
    sum += v;
    out_sub[(((long)b * T_) + t) * SUB + s] = v;
  }
  out_final[(long)b * T_ + t] = sum + vo;
}

extern "C" void kernel_launch(void* const* d_in, const int* in_sizes, int n_in,
                              void* d_out, int out_size, void* d_ws, size_t ws_size,
                              hipStream_t stream)
{
  const float* S_e    = (const float*)d_in[0];
  const float* S_i    = (const float*)d_in[1];
  const int*   testp  = (const int*)d_in[3];
  const float* g_e    = (const float*)d_in[4];
  const float* g_i    = (const float*)d_in[5];
  const float* Es     = (const float*)d_in[6];
  const float* Is     = (const float*)d_in[7];
  const float* We     = (const float*)d_in[8];
  const float* Wi     = (const float*)d_in[9];
  const float* W2     = (const float*)d_in[10];
  const float* b1     = (const float*)d_in[11];
  const float* Ce_raw = (const float*)d_in[12];
  const float* Ci_raw = (const float*)d_in[13];
  const float* Vo     = (const float*)d_in[14];

  float* ws   = (float*)d_ws;
  float* CwPE = ws;                      // 4*20*512 = 40960
  float* CwPI = ws + 40960;              // 20*512  = 10240
  float* Keff = ws + 51200;              // 80000
  float* e2   = ws + 131200;             // 200
  float* synE = ws + 131400;             // 1,600,000
  float* synI = synE + 1600000;          // 1,600,000
  float* subb = synI + 1600000;          // 1,600,000

  float* out     = (float*)d_out;
  float* o_final = out;                  // 80,000
  float* o_sub   = out + 80000;          // 1,600,000
  float* o_Ce    = out + 1680000;        // 40,000
  float* o_Ci    = out + 1720000;        // 10,000

  prep1_kernel<<<16, 256, 0, stream>>>(Ce_raw, Ci_raw, g_e, g_i, Es, Is, W2, testp,
                                       o_Ce, o_Ci, CwPE, CwPI, e2);
  prep2_kernel<<<(2 * SUB * HID * TNO + 255) / 256, 256, 0, stream>>>(We, Wi, Keff);
  gemm_syn_kernel<<<dim3(T_ / 16, B_), 256, 0, stream>>>(S_e, S_i, CwPE, CwPI, synE, synI);
  conv_kernel<<<dim3(20, SUB, B_), 256, 0, stream>>>(synE, synI, Keff, e2, b1, subb);
  final_kernel<<<dim3((T_ + 255) / 256, B_), 256, 0, stream>>>(subb, Vo, o_final, o_sub);
}

// Round 5
// 1063.449 us; speedup vs baseline: 1.0128x; 1.0128x over previous
//
#include <hip/hip_runtime.h>
#include <math.h>

#define B_   4
#define T_   20000
#define SUB  20
#define ENO  2000
#define INO  500
#define HID  10
#define NCOS 24
#define TNO  200

// ---------------- prep 1: softmax over subunit axis; CwP = padded slice-major C*exp(scale); e2 = exp(W2)
// CwPE layout: [(z*SUB + s)*512 + e'] for e' in [0,500), z = e/500. Pads [500,512) zeroed here too.
__global__ __launch_bounds__(256) void prep1_kernel(
    const float* __restrict__ Ce_raw, const float* __restrict__ Ci_raw,
    const float* __restrict__ ge, const float* __restrict__ gi,
    const float* __restrict__ Es, const float* __restrict__ Is,
    const float* __restrict__ W2, const int* __restrict__ testp,
    float* __restrict__ outCe, float* __restrict__ outCi,
    float* __restrict__ CwPE, float* __restrict__ CwPI, float* __restrict__ e2)
{
  int idx = blockIdx.x * 256 + threadIdx.x;
  int test = *testp;
  float scale = test ? 10000.f : 1000.f;
  if (idx < ENO + INO) {
    const float* raw; const float* g; float* outC; int n, col; float sc;
    if (idx < ENO) { raw = Ce_raw; g = ge; outC = outCe; n = ENO; col = idx;       sc = expf(Es[col]); }
    else           { raw = Ci_raw; g = gi; outC = outCi; n = INO; col = idx - ENO; sc = expf(Is[col]); }
    float v[SUB]; float m = -1e30f;
    #pragma unroll
    for (int s = 0; s < SUB; s++) {
      float x = raw[s * n + col];
      if (!test) x += g[s * n + col];
      x *= scale;
      v[s] = x; m = fmaxf(m, x);
    }
    float sum = 0.f;
    #pragma unroll
    for (int s = 0; s < SUB; s++) { v[s] = expf(v[s] - m); sum += v[s]; }
    float inv = 1.f / sum;
    if (idx < ENO) {
      int z = col / 500, e2c = col - z * 500;
      #pragma unroll
      for (int s = 0; s < SUB; s++) {
        float c = v[s] * inv; outC[s * n + col] = c;
        CwPE[((long)(z * SUB + s)) * 512 + e2c] = c * sc;
      }
    } else {
      #pragma unroll
      for (int s = 0; s < SUB; s++) {
        float c = v[s] * inv; outC[s * n + col] = c;
        CwPI[(long)s * 512 + col] = c * sc;
      }
    }
  } else if (idx < ENO + INO + SUB * HID) {
    int j = idx - (ENO + INO);
    e2[j] = expf(W2[j]);
  } else if (idx < ENO + INO + SUB * HID + 960 + 240) {
    int j = idx - (ENO + INO + SUB * HID);
    if (j < 960) { int z = j / 240, s = (j / 12) % SUB, c = j % 12; CwPE[((long)(z * SUB + s)) * 512 + 500 + c] = 0.f; }
    else         { int j2 = j - 960; int s = j2 / 12, c = j2 % 12;  CwPI[(long)s * 512 + 500 + c] = 0.f; }
  }
}

// ---------------- prep 2: effective kernels Keff[src][s][h][d] = sum_k W[s*HID+h,k] * basis(k,d)
__global__ __launch_bounds__(256) void prep2_kernel(
    const float* __restrict__ We, const float* __restrict__ Wi, float* __restrict__ Keff)
{
  int idx = blockIdx.x * 256 + threadIdx.x;
  if (idx >= 2 * SUB * HID * TNO) return;
  int d   = idx % TNO;
  int sh  = (idx / TNO) % (SUB * HID);
  int src = idx / (TNO * SUB * HID);
  const float* W = src ? Wi : We;           // [SUB*HID][NCOS]
  const float PIF = 3.14159265358979323846f;
  float raw = 6.0f * logf((float)d + 1.0f + 1e-7f);
  float acc = 0.f;
  #pragma unroll
  for (int k = 0; k < NCOS; k++) {
    float ph = 1.57079632679489662f * (float)k;
    if (raw >= ph - PIF && raw <= ph + PIF) {
      acc += W[sh * NCOS + k] * (0.5f * cosf(raw - ph) + 0.5f);
    }
  }
  Keff[idx] = acc;
}

// ---------------- GEMM: syn[b][s][t] = sum_e S[b,t,e] * Cw[s,e]
// Block = 16 t-rows x full K (z-loop over five 500-e slices).
// S staged via __builtin_amdgcn_global_load_lds width=16 (zero staging VGPRs, no spill):
// LDS is LINEAR (row stride 500 floats, 32 KB); per-lane GLOBAL address carries the
// row/col decomposition. Compute reads at stride 500 -> ~2-way bank aliasing (free).
// Cw read straight from global CwP (L1/L2-resident). 5 blocks/CU; TLP hides load phases.
// Lane split: rp=l&3 (rows), ep=l>>2 (16-way e). Tail: shfl_xor reduce over ep.
__global__ __launch_bounds__(256, 4) void gemm_syn_kernel(
    const float* __restrict__ S_e, const float* __restrict__ S_i,
    const float* __restrict__ CwPE, const float* __restrict__ CwPI,
    float* __restrict__ synE, float* __restrict__ synI)
{
  const int b  = blockIdx.y;
  const int t0 = blockIdx.x * 16;
  __shared__ __align__(16) float sS[2048 * 4];   // 32 KB; slice rows at stride 500; tail pad unread

  const int tid = threadIdx.x;
  const int l   = tid & 63;
  const int w   = tid >> 6;
  const int s0  = w * 5;
  const int rp  = l & 3;
  const int ep  = l >> 2;

  float acc[4][5] = {};

  const long rowE = ((long)b * T_ + t0) * ENO;
  const long rowI = ((long)b * T_ + t0) * INO;

  for (int z = 0; z < 5; z++) {
    const bool isE = (z < 4);
    const float* __restrict__ src = isE ? (S_e + rowE + z * 500) : (S_i + rowI);
    const int rs = isE ? ENO : INO;

    // stage slice z: 2000 float4 (16 rows x 125), direct global->LDS
    #pragma unroll
    for (int p = 0; p < 8; p++) {
      int c = w + 4 * p;              // chunk 0..31 (64 float4 each)
      int u = 64 * c + l;             // float4 index in slice
      u = u < 2000 ? u : 1999;        // tail lanes write LDS pad with dup data
      int r = u / 125, k = u - r * 125;
      const float* g = src + (long)r * rs + 4 * k;
      __builtin_amdgcn_global_load_lds(
          (const __attribute__((address_space(1))) void*)g,
          (__attribute__((address_space(3))) void*)(sS + 256 * c),
          16, 0, 0);
    }
    __syncthreads();   // vmcnt(0) drain inserted by compiler

    const float* __restrict__ cwb = isE ? (CwPE + ((long)z * SUB) * 512) : CwPI;
    #pragma unroll
    for (int step = 0; step < 8; step++) {
      const int e = 4 * ep + 64 * step;
      float4 cw[5];
      #pragma unroll
      for (int j = 0; j < 5; j++) cw[j] = *(const float4*)&cwb[(s0 + j) * 512 + e];
      #pragma unroll
      for (int tt = 0; tt < 4; tt++) {
        float4 sv = *(float4*)&sS[(rp + 4 * tt) * 500 + e];
        #pragma unroll
        for (int j = 0; j < 5; j++) {
          acc[tt][j] += sv.x * cw[j].x;
          acc[tt][j] += sv.y * cw[j].y;
          acc[tt][j] += sv.z * cw[j].z;
          acc[tt][j] += sv.w * cw[j].w;
        }
      }
    }

    if (z >= 3) {
      // reduce over ep (lane bits 2..5)
      #pragma unroll
      for (int mask = 4; mask <= 32; mask <<= 1)
        #pragma unroll
        for (int tt = 0; tt < 4; tt++)
          #pragma unroll
          for (int j = 0; j < 5; j++)
            acc[tt][j] += __shfl_xor(acc[tt][j], mask, 64);
      float* __restrict__ dst = (z == 3) ? synE : synI;
      if (l < 4) {
        #pragma unroll
        for (int j = 0; j < 5; j++)
          #pragma unroll
          for (int tt = 0; tt < 4; tt++)
            dst[((long)b * SUB + s0 + j) * T_ + t0 + rp + 4 * tt] = acc[tt][j];
      }
      #pragma unroll
      for (int tt = 0; tt < 4; tt++)
        #pragma unroll
        for (int j = 0; j < 5; j++) acc[tt][j] = 0.f;
    }
    __syncthreads();   // protect LDS before next slice's staging
  }
}

// ---------------- conv: pre[h,t] = sum_d Ke[h,d]*syn_e[t-d] + Ki[h,d]*syn_i[t-d]; tanh; combine over h
__global__ __launch_bounds__(256, 2) void conv_kernel(
    const float* __restrict__ synE, const float* __restrict__ synI,
    const float* __restrict__ Keff, const float* __restrict__ e2,
    const float* __restrict__ b1, float* __restrict__ sub_bst)
{
  const int chunk = blockIdx.x;       // 0..19
  const int s = blockIdx.y;
  const int b = blockIdx.z;
  const int cs = chunk * 1000;

  __shared__ __align__(16) float se[1200];
  __shared__ __align__(16) float si[1200];
  __shared__ __align__(16) float te[HID * TNO];
  __shared__ __align__(16) float ti[HID * TNO];
  __shared__ float se2[HID], sb[HID];

  const int tid = threadIdx.x;
  const float* __restrict__ pe = &synE[((long)b * SUB + s) * T_];
  const float* __restrict__ pin = &synI[((long)b * SUB + s) * T_];

  for (int i4 = tid; i4 < 300; i4 += 256) {
    int gt = cs - 200 + i4 * 4;
    float4 ve = make_float4(0.f, 0.f, 0.f, 0.f);
    float4 vi = make_float4(0.f, 0.f, 0.f, 0.f);
    if (gt >= 0) { ve = *(const float4*)&pe[gt]; vi = *(const float4*)&pin[gt]; }
    *(float4*)&se[i4 * 4] = ve;
    *(float4*)&si[i4 * 4] = vi;
  }
  const float* __restrict__ ke = &Keff[(long)s * HID * TNO];
  const float* __restrict__ ki = &Keff[((long)SUB + s) * HID * TNO];
  for (int i4 = tid; i4 < 500; i4 += 256) {
    *(float4*)&te[i4 * 4] = *(const float4*)&ke[i4 * 4];
    *(float4*)&ti[i4 * 4] = *(const float4*)&ki[i4 * 4];
  }
  if (tid < HID) { se2[tid] = e2[s * HID + tid]; sb[tid] = b1[s * HID + tid]; }
  __syncthreads();

  if (tid >= 250) return;
  const int lofs = 200 + 4 * tid;
  float so[4] = {0.f, 0.f, 0.f, 0.f};

  #pragma unroll
  for (int half = 0; half < 2; half++) {
    const int h0 = half * 5;
    float acc[5][4] = {};
    float we[8], wi[8];
    *(float4*)&we[4] = *(float4*)&se[lofs];
    *(float4*)&wi[4] = *(float4*)&si[lofs];
    for (int dstep = 0; dstep < 50; dstep++) {
      const int d0 = dstep * 4;
      *(float4*)&we[0] = *(float4*)&se[lofs - d0 - 4];
      *(float4*)&wi[0] = *(float4*)&si[lofs - d0 - 4];
      float4 tpe[5], tpi[5];
      #pragma unroll
      for (int h = 0; h < 5; h++) {
        tpe[h] = *(float4*)&te[(h0 + h) * TNO + d0];
        tpi[h] = *(float4*)&ti[(h0 + h) * TNO + d0];
      }
      #pragma unroll
      for (int dd = 0; dd < 4; dd++) {
        #pragma unroll
        for (int h = 0; h < 5; h++) {
          float tapeh = ((float*)&tpe[h])[dd];
          float tapih = ((float*)&tpi[h])[dd];
          #pragma unroll
          for (int j = 0; j < 4; j++) {
            acc[h][j] += tapeh * we[4 + j - dd];
            acc[h][j] += tapih * wi[4 + j - dd];
          }
        }
      }
      #pragma unroll
      for (int m = 0; m < 4; m++) { we[4 + m] = we[m]; wi[4 + m] = wi[m]; }
    }
    #pragma unroll
    for (int h = 0; h < 5; h++) {
      float eh = se2[h0 + h], bh = sb[h0 + h];
      #pragma unroll
      for (int j = 0; j < 4; j++) so[j] += eh * tanhf(acc[h][j] + bh);
    }
  }
  int t0 = cs + 4 * tid;
  *(float4*)&sub_bst[((long)b * SUB + s) * T_ + t0] = *(float4*)&so[0];
}

// ---------------- final: transpose sub_bst[b][s][t] -> sub_out[b][t][s], final[b][t] = sum_s + V_o
__global__ __launch_bounds__(256) void final_kernel(
    const float* __restrict__ sub_bst, const float* __restrict__ Vo,
    float* __restrict__ out_final, float* __restrict__ out_sub)
{
  int t = blockIdx.x * 256 + threadIdx.x;
  int b = blockIdx.y;
  if (t >= T_) return;
  float vo = Vo[0];
  float sum = 0.f;
  #pragma unroll
  for (int s = 0; s < SUB; s++) {
    float v = sub_bst[((long)b * SUB + s) * T_ + t];
    sum += v;
    out_sub[(((long)b * T_) + t) * SUB + s] = v;
  }
  out_final[(long)b * T_ + t] = sum + vo;
}

extern "C" void kernel_launch(void* const* d_in, const int* in_sizes, int n_in,
                              void* d_out, int out_size, void* d_ws, size_t ws_size,
                              hipStream_t stream)
{
  const float* S_e    = (const float*)d_in[0];
  const float* S_i    = (const float*)d_in[1];
  const int*   testp  = (const int*)d_in[3];
  const float* g_e    = (const float*)d_in[4];
  const float* g_i    = (const float*)d_in[5];
  const float* Es     = (const float*)d_in[6];
  const float* Is     = (const float*)d_in[7];
  const float* We     = (const float*)d_in[8];
  const float* Wi     = (const float*)d_in[9];
  const float* W2     = (const float*)d_in[10];
  const float* b1     = (const float*)d_in[11];
  const float* Ce_raw = (const float*)d_in[12];
  const float* Ci_raw = (const float*)d_in[13];
  const float* Vo     = (const float*)d_in[14];

  float* ws   = (float*)d_ws;
  float* CwPE = ws;                      // 4*20*512 = 40960
  float* CwPI = ws + 40960;              // 20*512  = 10240
  float* Keff = ws + 51200;              // 80000
  float* e2   = ws + 131200;             // 200
  float* synE = ws + 131400;             // 1,600,000
  float* synI = synE + 1600000;          // 1,600,000
  float* subb = synI + 1600000;          // 1,600,000

  float* out     = (float*)d_out;
  float* o_final = out;                  // 80,000
  float* o_sub   = out + 80000;          // 1,600,000
  float* o_Ce    = out + 1680000;        // 40,000
  float* o_Ci    = out + 1720000;        // 10,000

  prep1_kernel<<<16, 256, 0, stream>>>(Ce_raw, Ci_raw, g_e, g_i, Es, Is, W2, testp,
                                       o_Ce, o_Ci, CwPE, CwPI, e2);
  prep2_kernel<<<(2 * SUB * HID * TNO + 255) / 256, 256, 0, stream>>>(We, Wi, Keff);
  gemm_syn_kernel<<<dim3(T_ / 16, B_), 256, 0, stream>>>(S_e, S_i, CwPE, CwPI, synE, synI);
  conv_kernel<<<dim3(20, SUB, B_), 256, 0, stream>>>(synE, synI, Keff, e2, b1, subb);
  final_kernel<<<dim3((T_ + 255) / 256, B_), 256, 0, stream>>>(subb, Vo, o_final, o_sub);
}

// Round 6
// 795.347 us; speedup vs baseline: 1.3542x; 1.3371x over previous
//
#include <hip/hip_runtime.h>
#include <math.h>

#define B_   4
#define T_   20000
#define SUB  20
#define ENO  2000
#define INO  500
#define HID  10
#define NCOS 24
#define TNO  200
#define NSL  25      // 20 E slices + 5 I slices, each 100 e wide
#define SLW  100     // slice width (floats)
#define ROWS 64      // t-rows per block

// ---------------- prep 1: softmax over subunit axis; CwP[(z*20+s)*128 + e'] = C*exp(scale); e2 = exp(W2)
__global__ __launch_bounds__(256) void prep1_kernel(
    const float* __restrict__ Ce_raw, const float* __restrict__ Ci_raw,
    const float* __restrict__ ge, const float* __restrict__ gi,
    const float* __restrict__ Es, const float* __restrict__ Is,
    const float* __restrict__ W2, const int* __restrict__ testp,
    float* __restrict__ outCe, float* __restrict__ outCi,
    float* __restrict__ CwP, float* __restrict__ e2)
{
  int idx = blockIdx.x * 256 + threadIdx.x;
  int test = *testp;
  float scale = test ? 10000.f : 1000.f;
  if (idx < ENO + INO) {
    const float* raw; const float* g; float* outC; int n, col, zbase; float sc;
    if (idx < ENO) { raw = Ce_raw; g = ge; outC = outCe; n = ENO; col = idx;       zbase = 0;  sc = expf(Es[col]); }
    else           { raw = Ci_raw; g = gi; outC = outCi; n = INO; col = idx - ENO; zbase = 20; sc = expf(Is[col]); }
    float v[SUB]; float m = -1e30f;
    #pragma unroll
    for (int s = 0; s < SUB; s++) {
      float x = raw[s * n + col];
      if (!test) x += g[s * n + col];
      x *= scale;
      v[s] = x; m = fmaxf(m, x);
    }
    float sum = 0.f;
    #pragma unroll
    for (int s = 0; s < SUB; s++) { v[s] = expf(v[s] - m); sum += v[s]; }
    float inv = 1.f / sum;
    int z = zbase + col / SLW, ep = col % SLW;
    #pragma unroll
    for (int s = 0; s < SUB; s++) {
      float c = v[s] * inv;
      outC[s * n + col] = c;
      CwP[((long)(z * SUB + s)) * 128 + ep] = c * sc;
    }
  } else if (idx < ENO + INO + SUB * HID) {
    int j = idx - (ENO + INO);
    e2[j] = expf(W2[j]);
  } else if (idx < ENO + INO + SUB * HID + NSL * SUB * 28) {
    int j = idx - (ENO + INO + SUB * HID);
    int zs = j / 28, c = j % 28;
    CwP[(long)zs * 128 + SLW + c] = 0.f;     // zero pad [100,128)
  }
}

// ---------------- prep 2: effective kernels Keff[src][s][h][d] = sum_k W[s*HID+h,k] * basis(k,d)
__global__ __launch_bounds__(256) void prep2_kernel(
    const float* __restrict__ We, const float* __restrict__ Wi, float* __restrict__ Keff)
{
  int idx = blockIdx.x * 256 + threadIdx.x;
  if (idx >= 2 * SUB * HID * TNO) return;
  int d   = idx % TNO;
  int sh  = (idx / TNO) % (SUB * HID);
  int src = idx / (TNO * SUB * HID);
  const float* W = src ? Wi : We;           // [SUB*HID][NCOS]
  const float PIF = 3.14159265358979323846f;
  float raw = 6.0f * logf((float)d + 1.0f + 1e-7f);
  float acc = 0.f;
  #pragma unroll
  for (int k = 0; k < NCOS; k++) {
    float ph = 1.57079632679489662f * (float)k;
    if (raw >= ph - PIF && raw <= ph + PIF) {
      acc += W[sh * NCOS + k] * (0.5f * cosf(raw - ph) + 0.5f);
    }
  }
  Keff[idx] = acc;
}

// ---------------- GEMM: syn[b][s][t] = sum_e S[b,t,e] * Cw[s,e]
// Block = 64 t-rows (lane = row) x full K as 25 slices of 100 e. Wave w owns s 5w..5w+4.
// S: global_load_lds width=16 into 25.6KB LDS slice, double-buffered (51.2KB -> 3 blk/CU).
//    1600 float4 per slice = exactly 25 chunks of 64 lanes. Stage z+1 issued BEFORE
//    compute z; the only vmcnt ops are staging -> drained at end-of-iter barrier.
// Cw: wave-uniform pointer (readfirstlane) -> scalar s_load_dwordx4 (lgkmcnt, no vmcnt
//    entanglement), feeds v_fma as the SGPR operand. No e-split -> NO shuffle reduce.
__global__ __launch_bounds__(256, 2) void gemm_syn_kernel(
    const float* __restrict__ S_e, const float* __restrict__ S_i,
    const float* __restrict__ CwP,
    float* __restrict__ synE, float* __restrict__ synI)
{
  const int b  = blockIdx.y;
  const int t0 = blockIdx.x * ROWS;
  __shared__ __align__(16) float sS[2 * ROWS * SLW];   // 2 x 6400 floats

  const int tid = threadIdx.x;
  const int l   = tid & 63;
  const int w   = tid >> 6;
  const int s0u = __builtin_amdgcn_readfirstlane(w * 5);
  const int maxr = (T_ - 1) - t0;          // 63 normally, 31 for the last block

  float4 acc4[5];
  #pragma unroll
  for (int j = 0; j < 5; j++) acc4[j] = make_float4(0.f, 0.f, 0.f, 0.f);

  const long baseE = ((long)(b * T_ + t0)) * ENO;
  const long baseI = ((long)(b * T_ + t0)) * INO;

  // ---- stage slice 0 into buf 0
  {
    const float* __restrict__ src = S_e + baseE;
    #pragma unroll
    for (int p = 0; p < 7; p++) {
      int c = w + 4 * p;
      if (c < 25) {
        int u = 64 * c + l;
        int r = u / 25, k = u - 25 * r;
        if (r > maxr) r = maxr;
        const float* g = src + (long)r * ENO + 4 * k;
        __builtin_amdgcn_global_load_lds(
            (const __attribute__((address_space(1))) void*)g,
            (__attribute__((address_space(3))) void*)(sS + 256 * c),
            16, 0, 0);
      }
    }
  }
  __syncthreads();

  for (int z = 0; z < NSL; z++) {
    const int cur = z & 1;
    // ---- issue stage of slice z+1 into buf cur^1 (completes during compute)
    if (z + 1 < NSL) {
      const bool nE = (z + 1 < 20);
      const float* __restrict__ src = nE ? (S_e + baseE + (z + 1) * SLW)
                                         : (S_i + baseI + (z + 1 - 20) * SLW);
      const int rs = nE ? ENO : INO;
      float* dstb = sS + (cur ^ 1) * (ROWS * SLW);
      #pragma unroll
      for (int p = 0; p < 7; p++) {
        int c = w + 4 * p;
        if (c < 25) {
          int u = 64 * c + l;
          int r = u / 25, k = u - 25 * r;
          if (r > maxr) r = maxr;
          const float* g = src + (long)r * rs + 4 * k;
          __builtin_amdgcn_global_load_lds(
              (const __attribute__((address_space(1))) void*)g,
              (__attribute__((address_space(3))) void*)(dstb + 256 * c),
              16, 0, 0);
        }
      }
    }

    // ---- compute slice z: row l, s = s0u..s0u+4
    {
      const float* __restrict__ cwb = CwP + ((long)z * SUB + s0u) * 128;
      const float* sbase = sS + cur * (ROWS * SLW) + SLW * l;
      #pragma unroll
      for (int e4 = 0; e4 < 25; e4++) {
        float4 sv = *(const float4*)&sbase[4 * e4];
        #pragma unroll
        for (int j = 0; j < 5; j++) {
          float4 cw = *(const float4*)&cwb[j * 128 + 4 * e4];   // uniform -> s_load
          acc4[j].x += sv.x * cw.x;
          acc4[j].y += sv.y * cw.y;
          acc4[j].z += sv.z * cw.z;
          acc4[j].w += sv.w * cw.w;
        }
      }
    }

    // ---- output at end of E (z==19) and end of I (z==24)
    if (z == 19 || z == 24) {
      float* __restrict__ dst = (z == 19) ? synE : synI;
      if (t0 + l < T_) {
        #pragma unroll
        for (int j = 0; j < 5; j++) {
          float a = acc4[j].x + acc4[j].y + acc4[j].z + acc4[j].w;
          dst[((long)b * SUB + s0u + j) * T_ + t0 + l] = a;
        }
      }
      #pragma unroll
      for (int j = 0; j < 5; j++) acc4[j] = make_float4(0.f, 0.f, 0.f, 0.f);
    }
    __syncthreads();   // drains staging vmcnt; buffers swap safely
  }
}

// ---------------- conv: pre[h,t] = sum_d Ke[h,d]*syn_e[t-d] + Ki[h,d]*syn_i[t-d]; tanh; combine over h
__global__ __launch_bounds__(256, 2) void conv_kernel(
    const float* __restrict__ synE, const float* __restrict__ synI,
    const float* __restrict__ Keff, const float* __restrict__ e2,
    const float* __restrict__ b1, float* __restrict__ sub_bst)
{
  const int chunk = blockIdx.x;       // 0..19
  const int s = blockIdx.y;
  const int b = blockIdx.z;
  const int cs = chunk * 1000;

  __shared__ __align__(16) float se[1200];
  __shared__ __align__(16) float si[1200];
  __shared__ __align__(16) float te[HID * TNO];
  __shared__ __align__(16) float ti[HID * TNO];
  __shared__ float se2[HID], sb[HID];

  const int tid = threadIdx.x;
  const float* __restrict__ pe = &synE[((long)b * SUB + s) * T_];
  const float* __restrict__ pin = &synI[((long)b * SUB + s) * T_];

  for (int i4 = tid; i4 < 300; i4 += 256) {
    int gt = cs - 200 + i4 * 4;
    float4 ve = make_float4(0.f, 0.f, 0.f, 0.f);
    float4 vi = make_float4(0.f, 0.f, 0.f, 0.f);
    if (gt >= 0) { ve = *(const float4*)&pe[gt]; vi = *(const float4*)&pin[gt]; }
    *(float4*)&se[i4 * 4] = ve;
    *(float4*)&si[i4 * 4] = vi;
  }
  const float* __restrict__ ke = &Keff[(long)s * HID * TNO];
  const float* __restrict__ ki = &Keff[((long)SUB + s) * HID * TNO];
  for (int i4 = tid; i4 < 500; i4 += 256) {
    *(float4*)&te[i4 * 4] = *(const float4*)&ke[i4 * 4];
    *(float4*)&ti[i4 * 4] = *(const float4*)&ki[i4 * 4];
  }
  if (tid < HID) { se2[tid] = e2[s * HID + tid]; sb[tid] = b1[s * HID + tid]; }
  __syncthreads();

  if (tid >= 250) return;
  const int lofs = 200 + 4 * tid;
  float so[4] = {0.f, 0.f, 0.f, 0.f};

  #pragma unroll
  for (int half = 0; half < 2; half++) {
    const int h0 = half * 5;
    float acc[5][4] = {};
    float we[8], wi[8];
    *(float4*)&we[4] = *(float4*)&se[lofs];
    *(float4*)&wi[4] = *(float4*)&si[lofs];
    for (int dstep = 0; dstep < 50; dstep++) {
      const int d0 = dstep * 4;
      *(float4*)&we[0] = *(float4*)&se[lofs - d0 - 4];
      *(float4*)&wi[0] = *(float4*)&si[lofs - d0 - 4];
      float4 tpe[5], tpi[5];
      #pragma unroll
      for (int h = 0; h < 5; h++) {
        tpe[h] = *(float4*)&te[(h0 + h) * TNO + d0];
        tpi[h] = *(float4*)&ti[(h0 + h) * TNO + d0];
      }
      #pragma unroll
      for (int dd = 0; dd < 4; dd++) {
        #pragma unroll
        for (int h = 0; h < 5; h++) {
          float tapeh = ((float*)&tpe[h])[dd];
          float tapih = ((float*)&tpi[h])[dd];
          #pragma unroll
          for (int j = 0; j < 4; j++) {
            acc[h][j] += tapeh * we[4 + j - dd];
            acc[h][j] += tapih * wi[4 + j - dd];
          }
        }
      }
      #pragma unroll
      for (int m = 0; m < 4; m++) { we[4 + m] = we[m]; wi[4 + m] = wi[m]; }
    }
    #pragma unroll
    for (int h = 0; h < 5; h++) {
      float eh = se2[h0 + h], bh = sb[h0 + h];
      #pragma unroll
      for (int j = 0; j < 4; j++) so[j] += eh * tanhf(acc[h][j] + bh);
    }
  }
  int t0 = cs + 4 * tid;
  *(float4*)&sub_bst[((long)b * SUB + s) * T_ + t0] = *(float4*)&so[0];
}

// ---------------- final: transpose sub_bst[b][s][t] -> sub_out[b][t][s], final[b][t] = sum_s + V_o
__global__ __launch_bounds__(256) void final_kernel(
    const float* __restrict__ sub_bst, const float* __restrict__ Vo,
    float* __restrict__ out_final, float* __restrict__ out_sub)
{
  int t = blockIdx.x * 256 + threadIdx.x;
  int b = blockIdx.y;
  if (t >= T_) return;
  float vo = Vo[0];
  float sum = 0.f;
  #pragma unroll
  for (int s = 0; s < SUB; s++) {
    float v = sub_bst[((long)b * SUB + s) * T_ + t];
    sum += v;
    out_sub[(((long)b * T_) + t) * SUB + s] = v;
  }
  out_final[(long)b * T_ + t] = sum + vo;
}

extern "C" void kernel_launch(void* const* d_in, const int* in_sizes, int n_in,
                              void* d_out, int out_size, void* d_ws, size_t ws_size,
                              hipStream_t stream)
{
  const float* S_e    = (const float*)d_in[0];
  const float* S_i    = (const float*)d_in[1];
  const int*   testp  = (const int*)d_in[3];
  const float* g_e    = (const float*)d_in[4];
  const float* g_i    = (const float*)d_in[5];
  const float* Es     = (const float*)d_in[6];
  const float* Is     = (const float*)d_in[7];
  const float* We     = (const float*)d_in[8];
  const float* Wi     = (const float*)d_in[9];
  const float* W2     = (const float*)d_in[10];
  const float* b1     = (const float*)d_in[11];
  const float* Ce_raw = (const float*)d_in[12];
  const float* Ci_raw = (const float*)d_in[13];
  const float* Vo     = (const float*)d_in[14];

  float* ws   = (float*)d_ws;
  float* CwP  = ws;                      // 25*20*128 = 64000
  float* Keff = ws + 64000;              // 80000
  float* e2   = ws + 144000;             // 200
  float* synE = ws + 144200;             // 1,600,000
  float* synI = synE + 1600000;          // 1,600,000
  float* subb = synI + 1600000;          // 1,600,000

  float* out     = (float*)d_out;
  float* o_final = out;                  // 80,000
  float* o_sub   = out + 80000;          // 1,600,000
  float* o_Ce    = out + 1680000;        // 40,000
  float* o_Ci    = out + 1720000;        // 10,000

  prep1_kernel<<<66, 256, 0, stream>>>(Ce_raw, Ci_raw, g_e, g_i, Es, Is, W2, testp,
                                       o_Ce, o_Ci, CwP, e2);
  prep2_kernel<<<(2 * SUB * HID * TNO + 255) / 256, 256, 0, stream>>>(We, Wi, Keff);
  gemm_syn_kernel<<<dim3((T_ + ROWS - 1) / ROWS, B_), 256, 0, stream>>>(S_e, S_i, CwP, synE, synI);
  conv_kernel<<<dim3(20, SUB, B_), 256, 0, stream>>>(synE, synI, Keff, e2, b1, subb);
  final_kernel<<<dim3((T_ + 255) / 256, B_), 256, 0, stream>>>(subb, Vo, o_final, o_sub);
}